// Round 4
// baseline (96.641 us; speedup 1.0000x reference)
//
#include <hip/hip_runtime.h>
#include <stdint.h>

#define NTOK 16384
#define HID  4096
#define NEXP 64
#define TOKB 32
#define NSTEPS 64               // K-steps of 64 floats
#define PLANE (NEXP * HID)      // 262144 f16 per plane (512 KB)

typedef _Float16 f16;
typedef f16  f16x8 __attribute__((ext_vector_type(8)));
typedef float f32x4 __attribute__((ext_vector_type(4)));

typedef __attribute__((address_space(3))) uint32_t  lds_u32;
typedef __attribute__((address_space(1))) const uint32_t glb_u32;

// ---- pack w -> fragment-ordered fp16 hi/lo planes (R2/R3-proven) ----
// wp[p][ks_glob(128)][g(4)][lane(64)][j(8)]: e = g*16+(l&15), k = ks_glob*32+(l>>4)*8+j
__global__ __launch_bounds__(256)
void pack_w_kernel(const float* __restrict__ w, f16* __restrict__ wp) {
    int tid = blockIdx.x * 256 + threadIdx.x;
    int e = tid >> 9;
    int k = (tid & 511) << 3;
    const float* src = w + (size_t)e * HID + k;
    float4 v0 = *(const float4*)(src);
    float4 v1 = *(const float4*)(src + 4);
    float sv[8] = {v0.x, v0.y, v0.z, v0.w, v1.x, v1.y, v1.z, v1.w};
    f16x8 hi, lo;
    #pragma unroll
    for (int j = 0; j < 8; ++j) {
        float s = sv[j] * 64.0f;        // exact pow2 scale: lo avoids fp16 subnormals
        f16 h = (f16)s;
        hi[j] = h;
        lo[j] = (f16)(s - (float)h);
    }
    int ks   = k >> 5;
    int g    = e >> 4;
    int lane = ((k >> 3) & 3) * 16 + (e & 15);
    size_t dst = ((size_t)(ks * 4 + g) * 64 + lane) * 8;
    *(f16x8*)&wp[dst]         = hi;
    *(f16x8*)&wp[PLANE + dst] = lo;
}

// ---- main: gload_lds ring(3) + raw barrier + counted vmcnt(5); 8 waves/tile ----
__global__ __launch_bounds__(512, 4)
void topk_gate_kernel(const float* __restrict__ x,
                      const f16* __restrict__ wp,
                      float* __restrict__ out) {
    __shared__ __align__(16) float Abuf[3][TOKB * 64];   // 3 x 8 KB ring, f32 x-tile
    __shared__ float red[4][TOKB][4];

    const int t    = threadIdx.x;
    const int blk  = blockIdx.x;
    const int lane = t & 63;
    const int w    = t >> 6;       // 0..7
    const int tm   = w & 1;        // token half
    const int eg   = w >> 1;       // expert group (16 experts)
    const int col  = lane & 15;
    const int grp  = lane >> 4;

    // staging: wave w stages rows 4w..4w+3; LDS linear [row][unit], global unit
    // pre-swizzled u = p ^ (row&7) so the LINEAR LDS layout is the swizzled one.
    const int srow  = 4 * w + grp;
    const int sunit = col ^ (srow & 7);
    const float* asrc = x + ((size_t)blk * TOKB + srow) * HID + sunit * 4;

    // fragment read offsets (bytes within one ring buffer): row=tm*16+col,
    // k-unit u = ks*8 + grp*2 + h  ->  phys = u ^ (row&7)
    int fragOff[2][2];
    {
        const int arow = tm * 16 + col;
        #pragma unroll
        for (int ks = 0; ks < 2; ++ks)
            #pragma unroll
            for (int h = 0; h < 2; ++h)
                fragOff[ks][h] = arow * 256 + ((ks * 8 + grp * 2 + h) ^ (arow & 7)) * 16;
    }

    // B fragments: elem off = ((ks_glob*4 + eg)*64 + lane)*8; per (s,ks): +(2s+ks)*2048
    const f16* bw = wp + ((size_t)eg * 64 + lane) * 8;

    f32x4 acc = {0.f, 0.f, 0.f, 0.f};

    #define STAGE(s_, b_) do {                                                    \
        __builtin_amdgcn_global_load_lds(                                         \
            (glb_u32*)(const void*)(asrc + (size_t)(s_) * 64),                    \
            (lds_u32*)(void*)(&Abuf[b_][w * 256]), 16, 0, 0);                     \
    } while (0)

    f16x8 bh0[2], bl0[2], bh1[2], bl1[2], bh2[2], bl2[2];
    #define BLOAD(s_, BH, BL) do {                                                \
        _Pragma("unroll")                                                         \
        for (int ks = 0; ks < 2; ++ks) {                                          \
            size_t off_ = (size_t)(2 * (s_) + ks) * 2048;                         \
            BH[ks] = *(const f16x8*)(bw + off_);                                  \
            BL[ks] = *(const f16x8*)(bw + off_ + PLANE);                          \
        }                                                                         \
    } while (0)

    // prologue: queue = [stage0, B0x4, B1x4, stage1]  (10 outstanding)
    STAGE(0, 0);
    BLOAD(0, bh0, bl0);
    asm volatile("" ::: "memory");
    BLOAD(1, bh1, bl1);
    asm volatile("" ::: "memory");
    STAGE(1, 1);

    int bufc = 0;
    for (int s = 0; s < NSTEPS; ++s) {
        // own stage(s)+B(s) landed; stage(s+1)+B(s+1) stay in flight
        asm volatile("s_waitcnt vmcnt(5)" ::: "memory");
        __builtin_amdgcn_s_barrier();
        asm volatile("" ::: "memory");

        // issue gen s+2: B first, stage second (FIFO discipline for vmcnt math)
        const int s2 = (s + 2 < NSTEPS) ? s + 2 : NSTEPS - 1;
        BLOAD(s2, bh2, bl2);
        asm volatile("" ::: "memory");
        int bufn = bufc + 2; if (bufn >= 3) bufn -= 3;
        STAGE(s2, bufn);

        // consume buf[bufc] + B gen s
        const char* bp = (const char*)&Abuf[bufc][0];
        #pragma unroll
        for (int ks = 0; ks < 2; ++ks) {
            float4 q0 = *(const float4*)(bp + fragOff[ks][0]);
            float4 q1 = *(const float4*)(bp + fragOff[ks][1]);
            float v[8] = {q0.x, q0.y, q0.z, q0.w, q1.x, q1.y, q1.z, q1.w};
            f16x8 ah, al;
            #pragma unroll
            for (int j = 0; j < 8; ++j) {
                f16 h = (f16)v[j];
                ah[j] = h;
                al[j] = (f16)(v[j] - (float)h);
            }
            acc = __builtin_amdgcn_mfma_f32_16x16x32_f16(ah, bh0[ks], acc, 0, 0, 0);
            acc = __builtin_amdgcn_mfma_f32_16x16x32_f16(ah, bl0[ks], acc, 0, 0, 0);
            acc = __builtin_amdgcn_mfma_f32_16x16x32_f16(al, bh0[ks], acc, 0, 0, 0);
        }

        // rotate B generations
        #pragma unroll
        for (int ks = 0; ks < 2; ++ks) {
            bh0[ks] = bh1[ks]; bl0[ks] = bl1[ks];
            bh1[ks] = bh2[ks]; bl1[ks] = bl2[ks];
        }
        if (++bufc == 3) bufc = 0;
    }

    // ---- epilogue: top-2 over 16 experts per wave, merge 4 groups, softmax ----
    // C layout: lane holds C[token = grp*4+r (+tm*16)][expert = eg*16+col]
    #pragma unroll
    for (int r = 0; r < 4; ++r) {
        float v0 = acc[r]; int i0 = eg * 16 + col;
        float v1 = -INFINITY; int i1 = 0x7fffffff;
        #pragma unroll
        for (int m = 1; m <= 8; m <<= 1) {
            float ov0 = __shfl_xor(v0, m, 64);
            int   oi0 = __shfl_xor(i0, m, 64);
            float ov1 = __shfl_xor(v1, m, 64);
            int   oi1 = __shfl_xor(i1, m, 64);
            bool ob = (ov0 > v0) || (ov0 == v0 && oi0 < i0);
            if (ob) {
                bool k2 = (v0 > ov1) || (v0 == ov1 && i0 < oi1);
                v1 = k2 ? v0 : ov1; i1 = k2 ? i0 : oi1;
                v0 = ov0; i0 = oi0;
            } else {
                bool k2 = (ov0 > v1) || (ov0 == v1 && oi0 < i1);
                v1 = k2 ? ov0 : v1; i1 = k2 ? oi0 : i1;
            }
        }
        if (col == 0) {
            int tl = tm * 16 + grp * 4 + r;
            red[eg][tl][0] = v0; red[eg][tl][1] = (float)i0;
            red[eg][tl][2] = v1; red[eg][tl][3] = (float)i1;
        }
    }
    __syncthreads();

    if (t < TOKB) {
        float v0 = red[0][t][0]; int i0 = (int)red[0][t][1];
        float v1 = red[0][t][2]; int i1 = (int)red[0][t][3];
        #pragma unroll
        for (int g = 1; g < 4; ++g) {
            float b0 = red[g][t][0]; int bi0 = (int)red[g][t][1];
            float b1 = red[g][t][2]; int bi1 = (int)red[g][t][3];
            bool bb = (b0 > v0) || (b0 == v0 && bi0 < i0);
            if (bb) {
                bool k2 = (v0 > b1) || (v0 == b1 && i0 < bi1);
                float nv1 = k2 ? v0 : b1; int ni1 = k2 ? i0 : bi1;
                v0 = b0; i0 = bi0; v1 = nv1; i1 = ni1;
            } else {
                bool k2 = (b0 > v1) || (b0 == v1 && bi0 < i1);
                v1 = k2 ? b0 : v1; i1 = k2 ? bi0 : i1;
            }
        }
        // softmax over [v0, v1]; logits were scaled x64 via w
        float d  = (v1 - v0) * (1.0f / 64.0f);
        float e  = expf(d);
        float g0 = 1.0f / (1.0f + e);
        float g1 = e / (1.0f + e);

        int tok = blk * TOKB + t;
        out[(size_t)tok * 2 + 0] = g0;
        out[(size_t)tok * 2 + 1] = g1;
        out[(size_t)NTOK * 2 + (size_t)tok * 2 + 0] = (float)i0;
        out[(size_t)NTOK * 2 + (size_t)tok * 2 + 1] = (float)i1;
    }
}

extern "C" void kernel_launch(void* const* d_in, const int* in_sizes, int n_in,
                              void* d_out, int out_size, void* d_ws, size_t ws_size,
                              hipStream_t stream) {
    const float* x = (const float*)d_in[0];   // [16384, 4096] f32
    const float* w = (const float*)d_in[1];   // [64, 4096] f32
    float* out = (float*)d_out;               // gates [16384,2] then idx-as-f32 [16384,2]
    f16* wp = (f16*)d_ws;                     // 1 MB packed hi/lo planes
    (void)in_sizes; (void)n_in; (void)out_size; (void)ws_size;

    pack_w_kernel<<<dim3(128), dim3(256), 0, stream>>>(w, wp);
    topk_gate_kernel<<<dim3(NTOK / TOKB), dim3(512), 0, stream>>>(x, wp, out);
}

// Round 5
// 87.645 us; speedup vs baseline: 1.1027x; 1.1027x over previous
//
#include <hip/hip_runtime.h>
#include <stdint.h>

#define NTOK 16384
#define HID  4096
#define NEXP 64
#define BM   64
#define NSTEPS 64               // K-steps of 64 floats
#define PLANE (NEXP * HID)      // 262144 f16 per plane (512 KB)

typedef _Float16 f16;
typedef f16  f16x8 __attribute__((ext_vector_type(8)));
typedef float f32x4 __attribute__((ext_vector_type(4)));

typedef __attribute__((address_space(3))) uint32_t  lds_u32;
typedef __attribute__((address_space(1))) const uint32_t glb_u32;

// ---- pack w -> fragment-ordered fp16 hi/lo planes (R2-R4 proven) ----
// wp[p][ks_glob(128)][g(4)][lane(64)][j(8)]: e = g*16+(l&15), k = ks_glob*32+(l>>4)*8+j
__global__ __launch_bounds__(256)
void pack_w_kernel(const float* __restrict__ w, f16* __restrict__ wp) {
    int tid = blockIdx.x * 256 + threadIdx.x;
    int e = tid >> 9;
    int k = (tid & 511) << 3;
    const float* src = w + (size_t)e * HID + k;
    float4 v0 = *(const float4*)(src);
    float4 v1 = *(const float4*)(src + 4);
    float sv[8] = {v0.x, v0.y, v0.z, v0.w, v1.x, v1.y, v1.z, v1.w};
    f16x8 hi, lo;
    #pragma unroll
    for (int j = 0; j < 8; ++j) {
        float s = sv[j] * 64.0f;        // exact pow2 scale: lo avoids fp16 subnormals
        f16 h = (f16)s;
        hi[j] = h;
        lo[j] = (f16)(s - (float)h);
    }
    int ks   = k >> 5;
    int g    = e >> 4;
    int lane = ((k >> 3) & 3) * 16 + (e & 15);
    size_t dst = ((size_t)(ks * 4 + g) * 64 + lane) * 8;
    *(f16x8*)&wp[dst]         = hi;
    *(f16x8*)&wp[PLANE + dst] = lo;
}

// ---- main: A+B both gload_lds -> 4-slot ring, 1 barrier/step, vmcnt(4) ----
__global__ __launch_bounds__(512)
void topk_gate_kernel(const float* __restrict__ x,
                      const f16* __restrict__ wp,
                      float* __restrict__ out) {
    // slot = [A: 64 rows x 16 units of 16B (f32, XOR-swizzled)][B: 16 frags x 1KB f16]
    __shared__ __align__(16) char ring[4][32 * 1024];   // 128 KB

    const int t    = threadIdx.x;
    const int blk  = blockIdx.x;
    const int lane = t & 63;
    const int w    = t >> 6;       // 0..7
    const int col  = lane & 15;
    const int grp  = lane >> 4;
    const int wm   = w & 3;        // token quarter (16 tokens)
    const int wn   = w >> 2;       // expert half (32 experts)

    // ---- staging addresses (2 A-issues + 2 B-issues per thread per step) ----
    const float* asrc[2];
    const f16*   bsrc[2];
    int adst[2], bdst[2];
    #pragma unroll
    for (int i = 0; i < 2; ++i) {
        int r4  = w + 8 * i;                 // A frag: 4 rows
        int row = 4 * r4 + grp;
        int u   = col ^ (row & 15);          // pre-swizzled global unit (rule #21)
        asrc[i] = x + ((size_t)blk * BM + row) * HID + u * 4;
        adst[i] = r4 * 1024;                 // wave-uniform LDS byte base
        // B frag f = i*8 + w  <->  (plane=i, ks=w>>2, g=w&3); elem off s*4096 + w*512
        bsrc[i] = wp + (size_t)i * PLANE + (size_t)w * 512 + (size_t)lane * 8;
        bdst[i] = 16384 + (w + 8 * i) * 1024;
    }

    #define STAGE(s_, slot_) do {                                              \
        __builtin_amdgcn_global_load_lds(                                      \
            (glb_u32*)(const void*)(asrc[0] + (size_t)(s_) * 64),              \
            (lds_u32*)(void*)(ring[slot_] + adst[0]), 16, 0, 0);               \
        __builtin_amdgcn_global_load_lds(                                      \
            (glb_u32*)(const void*)(asrc[1] + (size_t)(s_) * 64),              \
            (lds_u32*)(void*)(ring[slot_] + adst[1]), 16, 0, 0);               \
        __builtin_amdgcn_global_load_lds(                                      \
            (glb_u32*)(const void*)(bsrc[0] + (size_t)(s_) * 4096),            \
            (lds_u32*)(void*)(ring[slot_] + bdst[0]), 16, 0, 0);               \
        __builtin_amdgcn_global_load_lds(                                      \
            (glb_u32*)(const void*)(bsrc[1] + (size_t)(s_) * 4096),            \
            (lds_u32*)(void*)(ring[slot_] + bdst[1]), 16, 0, 0);               \
        asm volatile("" ::: "memory");                                         \
    } while (0)

    // ---- compute-side LDS offsets ----
    const int arow = wm * 16 + col;
    int aoff[2][2], boff[2][2][2];
    #pragma unroll
    for (int ks = 0; ks < 2; ++ks) {
        #pragma unroll
        for (int h = 0; h < 2; ++h)
            aoff[ks][h] = arow * 256 + ((ks * 8 + grp * 2 + h) ^ (arow & 15)) * 16;
        #pragma unroll
        for (int e2 = 0; e2 < 2; ++e2) {
            int fb = ks * 4 + wn * 2 + e2;
            boff[ks][e2][0] = 16384 + fb * 1024 + lane * 16;          // hi plane
            boff[ks][e2][1] = 16384 + (8 + fb) * 1024 + lane * 16;    // lo plane
        }
    }

    f32x4 acc0 = {0.f, 0.f, 0.f, 0.f};   // experts wn*32 + col
    f32x4 acc1 = {0.f, 0.f, 0.f, 0.f};   // experts wn*32 + 16 + col

    #define COMPUTE(slot_) do {                                                \
        const char* Ls = ring[slot_];                                          \
        _Pragma("unroll")                                                      \
        for (int ks = 0; ks < 2; ++ks) {                                       \
            float4 q0 = *(const float4*)(Ls + aoff[ks][0]);                    \
            float4 q1 = *(const float4*)(Ls + aoff[ks][1]);                    \
            float vv[8] = {q0.x, q0.y, q0.z, q0.w, q1.x, q1.y, q1.z, q1.w};    \
            f16x8 ah, al;                                                      \
            _Pragma("unroll")                                                  \
            for (int j = 0; j < 8; ++j) {                                      \
                f16 h = (f16)vv[j];                                            \
                ah[j] = h;                                                     \
                al[j] = (f16)(vv[j] - (float)h);                               \
            }                                                                  \
            f16x8 bh0 = *(const f16x8*)(Ls + boff[ks][0][0]);                  \
            f16x8 bl0 = *(const f16x8*)(Ls + boff[ks][0][1]);                  \
            f16x8 bh1 = *(const f16x8*)(Ls + boff[ks][1][0]);                  \
            f16x8 bl1 = *(const f16x8*)(Ls + boff[ks][1][1]);                  \
            acc0 = __builtin_amdgcn_mfma_f32_16x16x32_f16(ah, bh0, acc0, 0, 0, 0); \
            acc0 = __builtin_amdgcn_mfma_f32_16x16x32_f16(ah, bl0, acc0, 0, 0, 0); \
            acc0 = __builtin_amdgcn_mfma_f32_16x16x32_f16(al, bh0, acc0, 0, 0, 0); \
            acc1 = __builtin_amdgcn_mfma_f32_16x16x32_f16(ah, bh1, acc1, 0, 0, 0); \
            acc1 = __builtin_amdgcn_mfma_f32_16x16x32_f16(ah, bl1, acc1, 0, 0, 0); \
            acc1 = __builtin_amdgcn_mfma_f32_16x16x32_f16(al, bh1, acc1, 0, 0, 0); \
        }                                                                      \
    } while (0)

    // ---- prologue: 2 steps in flight (8 issues/thread = 64 KB/CU) ----
    STAGE(0, 0);
    STAGE(1, 1);

    for (int s = 0; s < NSTEPS - 2; ++s) {
        asm volatile("s_waitcnt vmcnt(4)" ::: "memory");   // stage(s) landed; s+1 in flight
        __builtin_amdgcn_s_barrier();
        asm volatile("" ::: "memory");
        STAGE(s + 2, (s + 2) & 3);
        COMPUTE(s & 3);
    }
    asm volatile("s_waitcnt vmcnt(4)" ::: "memory");
    __builtin_amdgcn_s_barrier();
    asm volatile("" ::: "memory");
    COMPUTE((NSTEPS - 2) & 3);
    asm volatile("s_waitcnt vmcnt(0)" ::: "memory");
    __builtin_amdgcn_s_barrier();
    asm volatile("" ::: "memory");
    COMPUTE((NSTEPS - 1) & 3);

    // ---- epilogue: fused top-2 + softmax (R1-proven) ----
    // red[2][64][4] aliased into ring slot 0 (compute(63) reads slot 3 - disjoint)
    float (*red)[BM][4] = (float (*)[BM][4])(void*)ring;

    #pragma unroll
    for (int r = 0; r < 4; ++r) {
        float va = acc0[r], vb = acc1[r];
        int   ia = wn * 32 + col, ib = ia + 16;
        float v0, v1; int i0, i1;
        if (va >= vb) { v0 = va; i0 = ia; v1 = vb; i1 = ib; }
        else          { v0 = vb; i0 = ib; v1 = va; i1 = ia; }
        #pragma unroll
        for (int m = 1; m <= 8; m <<= 1) {
            float ov0 = __shfl_xor(v0, m, 64);
            int   oi0 = __shfl_xor(i0, m, 64);
            float ov1 = __shfl_xor(v1, m, 64);
            int   oi1 = __shfl_xor(i1, m, 64);
            bool ob = (ov0 > v0) || (ov0 == v0 && oi0 < i0);
            if (ob) {
                bool k2 = (v0 > ov1) || (v0 == ov1 && i0 < oi1);
                v1 = k2 ? v0 : ov1; i1 = k2 ? i0 : oi1;
                v0 = ov0; i0 = oi0;
            } else {
                bool k2 = (ov0 > v1) || (ov0 == v1 && oi0 < i1);
                v1 = k2 ? ov0 : v1; i1 = k2 ? oi0 : i1;
            }
        }
        if (col == 0) {
            int tl = wm * 16 + grp * 4 + r;
            red[wn][tl][0] = v0; red[wn][tl][1] = (float)i0;
            red[wn][tl][2] = v1; red[wn][tl][3] = (float)i1;
        }
    }
    __syncthreads();

    if (t < BM) {
        float v0 = red[0][t][0]; int i0 = (int)red[0][t][1];
        float v1 = red[0][t][2]; int i1 = (int)red[0][t][3];
        float b0 = red[1][t][0]; int bi0 = (int)red[1][t][1];
        float b1 = red[1][t][2]; int bi1 = (int)red[1][t][3];
        bool bb = (b0 > v0) || (b0 == v0 && bi0 < i0);
        if (bb) {
            bool k2 = (v0 > b1) || (v0 == b1 && i0 < bi1);
            float nv1 = k2 ? v0 : b1; int ni1 = k2 ? i0 : bi1;
            v0 = b0; i0 = bi0; v1 = nv1; i1 = ni1;
        } else {
            bool k2 = (b0 > v1) || (b0 == v1 && bi0 < i1);
            v1 = k2 ? b0 : v1; i1 = k2 ? bi0 : i1;
        }
        // softmax over [v0, v1]; logits were scaled x64 via w
        float d  = (v1 - v0) * (1.0f / 64.0f);
        float e  = expf(d);
        float g0 = 1.0f / (1.0f + e);
        float g1 = e / (1.0f + e);

        int tok = blk * BM + t;
        out[(size_t)tok * 2 + 0] = g0;
        out[(size_t)tok * 2 + 1] = g1;
        out[(size_t)NTOK * 2 + (size_t)tok * 2 + 0] = (float)i0;
        out[(size_t)NTOK * 2 + (size_t)tok * 2 + 1] = (float)i1;
    }
}

extern "C" void kernel_launch(void* const* d_in, const int* in_sizes, int n_in,
                              void* d_out, int out_size, void* d_ws, size_t ws_size,
                              hipStream_t stream) {
    const float* x = (const float*)d_in[0];   // [16384, 4096] f32
    const float* w = (const float*)d_in[1];   // [64, 4096] f32
    float* out = (float*)d_out;               // gates [16384,2] then idx-as-f32 [16384,2]
    f16* wp = (f16*)d_ws;                     // 1 MB packed hi/lo planes
    (void)in_sizes; (void)n_in; (void)out_size; (void)ws_size;

    pack_w_kernel<<<dim3(128), dim3(256), 0, stream>>>(w, wp);
    topk_gate_kernel<<<dim3(NTOK / BM), dim3(512), 0, stream>>>(x, wp, out);
}